// Round 19
// baseline (95.619 us; speedup 1.0000x reference)
//
#include <hip/hip_runtime.h>
#include <hip/hip_bf16.h>

// Shapes (fixed for this problem)
#define BB 2
#define NN 16
#define CC 256
#define KK 64
#define HW 4096
#define NH 8

typedef __attribute__((ext_vector_type(4))) float f32x4;
typedef __attribute__((ext_vector_type(8))) short s16x8;
typedef __attribute__((ext_vector_type(4))) short s16x4;

__device__ __forceinline__ short f2bf(float f) {
    __hip_bfloat16 h = __float2bfloat16(f);
    return *reinterpret_cast<short*>(&h);
}
__device__ __forceinline__ float bf2f(short s) {
    unsigned int u = ((unsigned int)(unsigned short)s) << 16;
    float f; __builtin_memcpy(&f, &u, 4); return f;
}

// ---------------------------------------------------------------------------
// K1 (fused): blocks [0,2048) = gates (beta/alpha per (b,n,k,h));
//             blocks [2048,2112) = softmax over K (emits kbf, kbfT).
// ---------------------------------------------------------------------------
__global__ __launch_bounds__(256) void k_pre(const float* __restrict__ state,
                                             const float* __restrict__ b_w,
                                             const float* __restrict__ a_w,
                                             const float* __restrict__ A_log,
                                             const float* __restrict__ dt_bias,
                                             float* __restrict__ betaH,
                                             float* __restrict__ alphaH,
                                             const float* __restrict__ km,
                                             short* __restrict__ kbf,
                                             short* __restrict__ kbfT) {
    __shared__ float red[4][2 * NH];
    const int tid = threadIdx.x;
    const int bid = blockIdx.x;

    if (bid < BB * NN * KK) {
        // ---------------- gates ----------------
        const int id = bid;            // (b*N+n)*K + k
        const int bn = id >> 6;
        const int k = id & 63;
        const float s = state[((size_t)bn * KK + k) * CC + tid];

        float pb[NH], pa[NH];
#pragma unroll
        for (int h = 0; h < NH; h++) {
            pb[h] = s * b_w[h * CC + tid];
            pa[h] = s * a_w[h * CC + tid];
        }
#pragma unroll
        for (int off = 32; off; off >>= 1) {
#pragma unroll
            for (int h = 0; h < NH; h++) {
                pb[h] += __shfl_down(pb[h], off, 64);
                pa[h] += __shfl_down(pa[h], off, 64);
            }
        }
        const int wave = tid >> 6, lane = tid & 63;
        if (lane == 0) {
#pragma unroll
            for (int h = 0; h < NH; h++) { red[wave][h] = pb[h]; red[wave][NH + h] = pa[h]; }
        }
        __syncthreads();
        const int h = tid >> 5;
        float braw = 0.f, araw = 0.f;
#pragma unroll
        for (int w = 0; w < 4; w++) { braw += red[w][h]; araw += red[w][NH + h]; }
        if ((tid & 31) == 0) {
            const float beta = 1.f / (1.f + __expf(-braw));
            const float xx = araw + dt_bias[h];
            const float sp = fmaxf(xx, 0.f) + log1pf(__expf(-fabsf(xx)));
            betaH[(size_t)id * NH + h] = beta;
            alphaH[(size_t)id * NH + h] = -__expf(A_log[h]) * sp;
        }
    } else {
        // ---------------- softmax (128 hw per block) ----------------
        const int sid = bid - BB * NN * KK;     // 0..63
        const int b = sid >> 5;                 // 32 blocks per b
        const int w = tid >> 6, lane = tid & 63;
        const int hw = (sid & 31) * 128 + w * 32 + (lane & 31);
        const int half = lane >> 5;             // k in [half*32, half*32+32)
        const float* p = km + ((size_t)b * KK + half * 32) * HW + hw;
        float x[32];
        float m = -1e30f;
#pragma unroll
        for (int k = 0; k < 32; k++) { x[k] = p[(size_t)k * HW]; m = fmaxf(m, x[k]); }
        m = fmaxf(m, __shfl_xor(m, 32, 64));
        float s = 0.f;
#pragma unroll
        for (int k = 0; k < 32; k++) { x[k] = __expf(x[k] - m); s += x[k]; }
        s += __shfl_xor(s, 32, 64);
        const float inv = 1.f / s;
        short* q2 = kbf + ((size_t)b * KK + half * 32) * HW + hw;
#pragma unroll
        for (int k = 0; k < 32; k++) {
            x[k] *= inv;
            q2[(size_t)k * HW] = f2bf(x[k]);
        }
        short* q3 = kbfT + ((size_t)b * HW + hw) * KK + half * 32;
#pragma unroll
        for (int k8 = 0; k8 < 32; k8 += 8) {
            s16x8 v;
#pragma unroll
            for (int j = 0; j < 8; j++) v[j] = f2bf(x[k8 + j]);
            *(s16x8*)(q3 + k8) = v;
        }
    }
}

// ---------------------------------------------------------------------------
// K_vg (merged vkt + gram, one launch — both depend only on k_pre):
// blocks [0,512): split-K vkt partials (r12/r13 body, unchanged);
// blocks [512,4672): gram pairs, 512 threads, 8 bf16/thread, scratch aliased
// onto Bs (no extra LDS -> still 2 blocks/CU at 80KB). Gram blocks drain
// into the vkt tail, hiding their exec + one launch gap.
// ---------------------------------------------------------------------------
__global__ __launch_bounds__(512) void k_vg(const short* __restrict__ kbf,
                                            const float* __restrict__ value,
                                            short* __restrict__ pbuf,
                                            float* __restrict__ gram) {
    __shared__ short Bs[2][256 * 64];   // value tile bf16, 32KB per buffer
    __shared__ short As[2][64 * 64];    // kbf  tile bf16,  8KB per buffer

    const int tid = threadIdx.x;
    const int bid = blockIdx.x;
    const int w = tid >> 6, lane = tid & 63;

    if (bid >= BB * NN * 16) {
        // ---------------- gram: pair t0, full 4096-hw dot ----------------
        const int t0 = bid - BB * NN * 16;      // 0..4159
        const int b = (t0 >= 2080) ? 1 : 0;
        const int t = t0 - b * 2080;
        int k = (int)((sqrtf(8.f * (float)t + 1.f) - 1.f) * 0.5f);
        while ((k + 1) * (k + 2) / 2 <= t) k++;
        while (k * (k + 1) / 2 > t) k--;
        const int j = t - k * (k + 1) / 2;

        const short* pa = kbf + ((size_t)b * KK + k) * HW + tid * 8;
        const short* pbp = kbf + ((size_t)b * KK + j) * HW + tid * 8;
        const s16x8 a0 = *(const s16x8*)pa;
        const s16x8 b0 = *(const s16x8*)pbp;
        float s = 0.f;
#pragma unroll
        for (int e = 0; e < 8; e++) s = fmaf(bf2f(a0[e]), bf2f(b0[e]), s);
#pragma unroll
        for (int off = 32; off; off >>= 1) s += __shfl_down(s, off, 64);
        float* redG = (float*)&Bs[0][0];        // alias vkt staging (unused here)
        if (lane == 0) redG[w] = s;
        __syncthreads();
        if (tid == 0) {
            float tot = 0.f;
#pragma unroll
            for (int r = 0; r < 8; r++) tot += redG[r];
            gram[((size_t)b * KK + k) * KK + j] = tot;
            gram[((size_t)b * KK + j) * KK + k] = tot;
        }
        return;
    }

    // ---------------- vkt split-K (r12/r13 body, unchanged) ----------------
    const int id = bid;                 // bn*16 + hs
    const int hs = id & 15;
    const int bn = id >> 4;
    const int b  = bn >> 4;
    const int l15 = lane & 15, hi = lane >> 4;
    const int hw0 = hs * 256;

    const int sr = tid >> 3;            // 0..63
    const int sj = tid & 7;             // 0..7
    const float* vbase = value + (size_t)bn * CC * HW + hw0;
    const short* abase = kbf + ((size_t)b * KK + sr) * HW + hw0 + sj * 8;

    f32x4 stgB[2][4][2];
    s16x8 stgA[2];

#define LOADREG(set_, t_)                                                      \
    {                                                                          \
        _Pragma("unroll") for (int i = 0; i < 4; i++) {                        \
            const float* p_ = vbase + (size_t)(sr + i * 64) * HW               \
                              + (t_) * 64 + sj * 8;                            \
            stgB[set_][i][0] = *(const f32x4*)p_;                              \
            stgB[set_][i][1] = *(const f32x4*)(p_ + 4);                        \
        }                                                                      \
        stgA[set_] = *(const s16x8*)(abase + (t_) * 64);                       \
    }
#define WRITE_LDS(set_, buf_)                                                  \
    {                                                                          \
        _Pragma("unroll") for (int i = 0; i < 4; i++) {                        \
            const int r_ = sr + i * 64;                                        \
            s16x8 tv_;                                                         \
            _Pragma("unroll") for (int e = 0; e < 4; e++) {                    \
                tv_[e]     = f2bf(stgB[set_][i][0][e]);                        \
                tv_[4 + e] = f2bf(stgB[set_][i][1][e]);                        \
            }                                                                  \
            *(s16x8*)&Bs[buf_][r_ * 64 + ((sj ^ (r_ & 7)) * 8)] = tv_;         \
        }                                                                      \
        *(s16x8*)&As[buf_][sr * 64 + ((sj ^ (sr & 7)) * 8)] = stgA[set_];      \
    }

    f32x4 acc[2][4];                    // [c-tile m2][k-tile n4]
#pragma unroll
    for (int m2 = 0; m2 < 2; m2++)
#pragma unroll
        for (int n4 = 0; n4 < 4; n4++) acc[m2][n4] = (f32x4){0.f, 0.f, 0.f, 0.f};

    // prologue
    LOADREG(0, 0);
    LOADREG(1, 1);
    WRITE_LDS(0, 0);
    asm volatile("s_waitcnt lgkmcnt(0)" ::: "memory");
    __builtin_amdgcn_s_barrier();

#pragma unroll
    for (int t = 0; t < 4; t++) {
        const int buf = t & 1;
        if (t + 2 < 4) LOADREG(buf, t + 2);          // HBM prefetch, 2 ahead
        if (t + 1 < 4) WRITE_LDS((t + 1) & 1, (t + 1) & 1);  // stage NEXT buffer

        const int swz = l15 & 7;
#pragma unroll
        for (int s = 0; s < 2; s++) {
            s16x8 vfr[2];
#pragma unroll
            for (int m2 = 0; m2 < 2; m2++)
                vfr[m2] = *(const s16x8*)&Bs[buf][(w * 32 + m2 * 16 + l15) * 64 +
                                                 (((s * 4 + hi) ^ swz) * 8)];
#pragma unroll
            for (int n4 = 0; n4 < 4; n4++) {
                const s16x8 afr = *(const s16x8*)&As[buf][(n4 * 16 + l15) * 64 +
                                                          (((s * 4 + hi) ^ swz) * 8)];
                acc[0][n4] = __builtin_amdgcn_mfma_f32_16x16x32_bf16(vfr[0], afr,
                                                                     acc[0][n4], 0, 0, 0);
                acc[1][n4] = __builtin_amdgcn_mfma_f32_16x16x32_bf16(vfr[1], afr,
                                                                     acc[1][n4], 0, 0, 0);
            }
        }
        if (t + 1 < 4) {
            asm volatile("s_waitcnt lgkmcnt(0)" ::: "memory");
            __builtin_amdgcn_s_barrier();            // single barrier per iter
        }
    }
#undef LOADREG
#undef WRITE_LDS

    // bf16 partial, store-order-native layout, chunk radix 8 (8 waves)
#pragma unroll
    for (int m2 = 0; m2 < 2; m2++)
#pragma unroll
        for (int n4 = 0; n4 < 4; n4++) {
            s16x4 v;
#pragma unroll
            for (int r = 0; r < 4; r++) v[r] = f2bf(acc[m2][n4][r]);
            *(s16x4*)(pbuf + ((((size_t)(id * 8 + w) * 2 + m2) * 4 + n4) * 64
                              + lane) * 4) = v;
        }
}

// ---------------------------------------------------------------------------
// K_cr (fused combine + readout): grid = bn(32) x ct(16) = 512 blocks,
// 512 threads (8 waves). Phase A (combine + gates) on tid<256.
// Phase B: LDS store-transpose -> 1KB fully-contiguous stores (r18, best).
// ---------------------------------------------------------------------------
__global__ __launch_bounds__(512) void k_cr(const short* __restrict__ pbuf,
                                            const float* __restrict__ gram,
                                            const float* __restrict__ state,
                                            const float* __restrict__ betaH,
                                            const float* __restrict__ alphaH,
                                            const short* __restrict__ kbfT,
                                            float* __restrict__ out) {
    const int tid = threadIdx.x;
    const int id = blockIdx.x;        // bn*16 + ct
    const int ct = id & 15;
    const int bn = id >> 4;
    const int b  = bn >> 4;
    const int head = ct >> 1;
    const int wi = ct >> 1, m2 = ct & 1;

    __shared__ float gramL[KK][65];
    __shared__ float stL[KK][17];
    __shared__ float alphaL[KK], betaL[KK];
    __shared__ float nsb[KK][17];
    __shared__ short nsB[16][72];       // bf16, k-contiguous, padded
    __shared__ float osb[2][16][260];   // store-transpose tile, 2-way banks

    for (int i = tid; i < KK * KK; i += 512)
        gramL[i >> 6][i & 63] = gram[(size_t)b * KK * KK + i];
    for (int i = tid; i < KK * 16; i += 512)
        stL[i >> 4][i & 15] = state[((size_t)bn * KK + (i >> 4)) * CC + ct * 16 + (i & 15)];
    if (tid < KK) {
        alphaL[tid] = alphaH[((size_t)bn * KK + tid) * NH + head];
        betaL[tid]  = betaH[((size_t)bn * KK + tid) * NH + head];
    }
    __syncthreads();

    if (tid < 256) {
        const int k = tid >> 2, cq = (tid & 3) * 4;
        const int n4 = k >> 4, l15k = k & 15, hi4 = tid & 3;

        float vkt[4] = {0.f, 0.f, 0.f, 0.f};
#pragma unroll
        for (int hs = 0; hs < 16; hs++) {
            const int slab = bn * 16 + hs;
            const s16x4 p = *(const s16x4*)(pbuf +
                ((((size_t)(slab * 8 + wi) * 2 + m2) * 4 + n4) * 64 + hi4 * 16 + l15k) * 4);
#pragma unroll
            for (int i = 0; i < 4; i++) vkt[i] += bf2f(p[i]);
        }

        float vk[4] = {0.f, 0.f, 0.f, 0.f};
#pragma unroll 8
        for (int j = 0; j < KK; j++) {
            const float g = gramL[k][j];
            vk[0] = fmaf(g, stL[j][cq + 0], vk[0]);
            vk[1] = fmaf(g, stL[j][cq + 1], vk[1]);
            vk[2] = fmaf(g, stL[j][cq + 2], vk[2]);
            vk[3] = fmaf(g, stL[j][cq + 3], vk[3]);
        }
        const float al = alphaL[k], be = betaL[k];
#pragma unroll
        for (int i = 0; i < 4; i++)
            nsb[k][cq + i] = al * (stL[k][cq + i] - be * vk[i]) + be * vkt[i];
    }
    __syncthreads();

    if (tid < 256) {   // nsb (f32, [k][c]) -> nsB (bf16, [c][k])
        const int c = tid >> 4, k4 = (tid & 15) * 4;
        s16x4 v;
#pragma unroll
        for (int i = 0; i < 4; i++) v[i] = f2bf(nsb[k4 + i][c]);
        *(s16x4*)&nsB[c][k4] = v;
    }
    __syncthreads();

    // ---------------- phase B: readout with LDS store-transpose ----------------
    const int w8 = tid >> 6, lane = tid & 63;
    const int l15 = lane & 15, hi = lane >> 4;

    const s16x8 cf0 = *(const s16x8*)&nsB[l15][hi * 8];        // B-frag, k 0..31
    const s16x8 cf1 = *(const s16x8*)&nsB[l15][32 + hi * 8];   // B-frag, k 32..63

    const short* kb = kbfT + ((size_t)b * HW + l15) * KK + hi * 8;
    const int sc = tid >> 6;            // store row c (0..7, +8 second pass)
    const int sch = tid & 63;           // store chunk (x f32x4)
    float* orow0 = out + ((size_t)bn * CC + ct * 16 + sc) * HW;
    float* orow1 = out + ((size_t)bn * CC + ct * 16 + sc + 8) * HW;

#pragma unroll 2
    for (int it = 0; it < 16; ++it) {   // 256 hw per iter
        const int hwb = it * 256;
        const int pb = it & 1;
#pragma unroll
        for (int t = 0; t < 2; ++t) {
            const int hw0 = hwb + w8 * 32 + t * 16;
            const short* Bp = kb + (size_t)hw0 * KK;
            const s16x8 hwf0 = *(const s16x8*)Bp;
            const s16x8 hwf1 = *(const s16x8*)(Bp + 32);
            f32x4 acc = (f32x4){0.f, 0.f, 0.f, 0.f};
            acc = __builtin_amdgcn_mfma_f32_16x16x32_bf16(hwf0, cf0, acc, 0, 0, 0);
            acc = __builtin_amdgcn_mfma_f32_16x16x32_bf16(hwf1, cf1, acc, 0, 0, 0);
            // D: col = l15 = c, row = hi*4+r = hw offset within 16-hw tile
            *(f32x4*)&osb[pb][l15][w8 * 32 + t * 16 + hi * 4] = acc;
        }
        __syncthreads();                // osb[pb] complete; prev readers done
        const f32x4 v0 = *(const f32x4*)&osb[pb][sc][sch * 4];
        const f32x4 v1 = *(const f32x4*)&osb[pb][sc + 8][sch * 4];
        *(f32x4*)&orow0[hwb + sch * 4] = v0;   // 1KB contiguous per wave
        *(f32x4*)&orow1[hwb + sch * 4] = v1;
    }
}

// ---------------------------------------------------------------------------
extern "C" void kernel_launch(void* const* d_in, const int* in_sizes, int n_in,
                              void* d_out, int out_size, void* d_ws, size_t ws_size,
                              hipStream_t stream) {
    const float* value   = (const float*)d_in[0];
    const float* key_map = (const float*)d_in[1];
    const float* state   = (const float*)d_in[2];
    const float* b_w     = (const float*)d_in[3];
    const float* a_w     = (const float*)d_in[4];
    const float* A_log   = (const float*)d_in[5];
    const float* dt_bias = (const float*)d_in[6];
    float* out = (float*)d_out;

    short* kbf   = (short*)d_ws;              // B*K*HW bf16     = 524288 sh
    short* kbfT  = kbf + 524288;              // B*HW*K bf16     = 524288 sh
    float* gram  = (float*)(kbfT + 524288);   // B*K*K           =   8192 f32
    float* betaH = gram + 8192;               // B*N*K*NH        =  16384 f32
    float* alphaH= betaH + 16384;             // B*N*K*NH        =  16384 f32
    short* pbufB = (short*)(alphaH + 16384);  // 512*16384 bf16  = 16 MB
    // total ~18.5 MB of d_ws

    k_pre<<<BB * NN * KK + BB * (HW / 128), 256, 0, stream>>>(
        state, b_w, a_w, A_log, dt_bias, betaH, alphaH, key_map, kbf, kbfT);
    k_vg<<<BB * NN * 16 + BB * 2080, 512, 0, stream>>>(kbf, value, pbufB, gram);
    k_cr<<<BB * NN * 16, 512, 0, stream>>>(pbufB, gram, state, betaH, alphaH,
                                           kbfT, out);
}

// Round 20
// 92.740 us; speedup vs baseline: 1.0310x; 1.0310x over previous
//
#include <hip/hip_runtime.h>
#include <hip/hip_bf16.h>

// Shapes (fixed for this problem)
#define BB 2
#define NN 16
#define CC 256
#define KK 64
#define HW 4096
#define NH 8

typedef __attribute__((ext_vector_type(4))) float f32x4;
typedef __attribute__((ext_vector_type(8))) short s16x8;
typedef __attribute__((ext_vector_type(4))) short s16x4;

__device__ __forceinline__ short f2bf(float f) {
    __hip_bfloat16 h = __float2bfloat16(f);
    return *reinterpret_cast<short*>(&h);
}
__device__ __forceinline__ float bf2f(short s) {
    unsigned int u = ((unsigned int)(unsigned short)s) << 16;
    float f; __builtin_memcpy(&f, &u, 4); return f;
}

// ---------------------------------------------------------------------------
// K1 (fused): blocks [0,2048) = gates (beta/alpha per (b,n,k,h));
//             blocks [2048,2112) = softmax over K (emits kbf, kbfT).
// ---------------------------------------------------------------------------
__global__ __launch_bounds__(256) void k_pre(const float* __restrict__ state,
                                             const float* __restrict__ b_w,
                                             const float* __restrict__ a_w,
                                             const float* __restrict__ A_log,
                                             const float* __restrict__ dt_bias,
                                             float* __restrict__ betaH,
                                             float* __restrict__ alphaH,
                                             const float* __restrict__ km,
                                             short* __restrict__ kbf,
                                             short* __restrict__ kbfT) {
    __shared__ float red[4][2 * NH];
    const int tid = threadIdx.x;
    const int bid = blockIdx.x;

    if (bid < BB * NN * KK) {
        // ---------------- gates ----------------
        const int id = bid;            // (b*N+n)*K + k
        const int bn = id >> 6;
        const int k = id & 63;
        const float s = state[((size_t)bn * KK + k) * CC + tid];

        float pb[NH], pa[NH];
#pragma unroll
        for (int h = 0; h < NH; h++) {
            pb[h] = s * b_w[h * CC + tid];
            pa[h] = s * a_w[h * CC + tid];
        }
#pragma unroll
        for (int off = 32; off; off >>= 1) {
#pragma unroll
            for (int h = 0; h < NH; h++) {
                pb[h] += __shfl_down(pb[h], off, 64);
                pa[h] += __shfl_down(pa[h], off, 64);
            }
        }
        const int wave = tid >> 6, lane = tid & 63;
        if (lane == 0) {
#pragma unroll
            for (int h = 0; h < NH; h++) { red[wave][h] = pb[h]; red[wave][NH + h] = pa[h]; }
        }
        __syncthreads();
        const int h = tid >> 5;
        float braw = 0.f, araw = 0.f;
#pragma unroll
        for (int w = 0; w < 4; w++) { braw += red[w][h]; araw += red[w][NH + h]; }
        if ((tid & 31) == 0) {
            const float beta = 1.f / (1.f + __expf(-braw));
            const float xx = araw + dt_bias[h];
            const float sp = fmaxf(xx, 0.f) + log1pf(__expf(-fabsf(xx)));
            betaH[(size_t)id * NH + h] = beta;
            alphaH[(size_t)id * NH + h] = -__expf(A_log[h]) * sp;
        }
    } else {
        // ---------------- softmax (128 hw per block) ----------------
        const int sid = bid - BB * NN * KK;     // 0..63
        const int b = sid >> 5;                 // 32 blocks per b
        const int w = tid >> 6, lane = tid & 63;
        const int hw = (sid & 31) * 128 + w * 32 + (lane & 31);
        const int half = lane >> 5;             // k in [half*32, half*32+32)
        const float* p = km + ((size_t)b * KK + half * 32) * HW + hw;
        float x[32];
        float m = -1e30f;
#pragma unroll
        for (int k = 0; k < 32; k++) { x[k] = p[(size_t)k * HW]; m = fmaxf(m, x[k]); }
        m = fmaxf(m, __shfl_xor(m, 32, 64));
        float s = 0.f;
#pragma unroll
        for (int k = 0; k < 32; k++) { x[k] = __expf(x[k] - m); s += x[k]; }
        s += __shfl_xor(s, 32, 64);
        const float inv = 1.f / s;
        short* q2 = kbf + ((size_t)b * KK + half * 32) * HW + hw;
#pragma unroll
        for (int k = 0; k < 32; k++) {
            x[k] *= inv;
            q2[(size_t)k * HW] = f2bf(x[k]);
        }
        short* q3 = kbfT + ((size_t)b * HW + hw) * KK + half * 32;
#pragma unroll
        for (int k8 = 0; k8 < 32; k8 += 8) {
            s16x8 v;
#pragma unroll
            for (int j = 0; j < 8; j++) v[j] = f2bf(x[k8 + j]);
            *(s16x8*)(q3 + k8) = v;
        }
    }
}

// ---------------------------------------------------------------------------
// K2: gram[b,k,j] = sum_hw kn[b,k,hw]*kn[b,j,hw]. Symmetric (k>=j, mirror).
// ---------------------------------------------------------------------------
__global__ __launch_bounds__(256) void k_gram(const short* __restrict__ kbf,
                                              float* __restrict__ gram) {
    const int tid = threadIdx.x;
    const int id = blockIdx.x;              // b*2080 + t
    const int b = (id >= 2080) ? 1 : 0;
    const int t = id - b * 2080;
    int k = (int)((sqrtf(8.f * (float)t + 1.f) - 1.f) * 0.5f);
    while ((k + 1) * (k + 2) / 2 <= t) k++;
    while (k * (k + 1) / 2 > t) k--;
    const int j = t - k * (k + 1) / 2;

    const short* pa = kbf + ((size_t)b * KK + k) * HW + tid * 16;
    const short* pb = kbf + ((size_t)b * KK + j) * HW + tid * 16;
    const s16x8 a0 = *(const s16x8*)pa, a1 = *(const s16x8*)(pa + 8);
    const s16x8 b0 = *(const s16x8*)pb, b1 = *(const s16x8*)(pb + 8);
    float s = 0.f;
#pragma unroll
    for (int i = 0; i < 8; i++) {
        s = fmaf(bf2f(a0[i]), bf2f(b0[i]), s);
        s = fmaf(bf2f(a1[i]), bf2f(b1[i]), s);
    }
#pragma unroll
    for (int off = 32; off; off >>= 1) s += __shfl_down(s, off, 64);
    __shared__ float red[4];
    if ((tid & 63) == 0) red[tid >> 6] = s;
    __syncthreads();
    if (tid == 0) {
        const float tot = red[0] + red[1] + red[2] + red[3];
        gram[((size_t)b * KK + k) * KK + j] = tot;
        gram[((size_t)b * KK + j) * KK + k] = tot;
    }
}

// ---------------------------------------------------------------------------
// K4a (MFMA, split-K): partial vkt[k, all 256 c] per 256-hw slab.
// Grid = bn(32) x hs(16) = 512 blocks, 512 threads (8 waves).
// Single barrier per iteration; bf16 partials, store-order-native layout,
// chunk radix 8. (Unchanged from r12/r13/r18 — debugged & passing.)
// ---------------------------------------------------------------------------
__global__ __launch_bounds__(512) void k_vkt_part(const short* __restrict__ kbf,
                                                  const float* __restrict__ value,
                                                  short* __restrict__ pbuf) {
    const int tid = threadIdx.x;
    const int id = blockIdx.x;          // bn*16 + hs
    const int hs = id & 15;
    const int bn = id >> 4;
    const int b  = bn >> 4;
    const int w = tid >> 6, lane = tid & 63;
    const int l15 = lane & 15, hi = lane >> 4;
    const int hw0 = hs * 256;

    __shared__ short Bs[2][256 * 64];   // value tile bf16, 32KB per buffer
    __shared__ short As[2][64 * 64];    // kbf  tile bf16,  8KB per buffer

    const int sr = tid >> 3;            // 0..63
    const int sj = tid & 7;             // 0..7
    const float* vbase = value + (size_t)bn * CC * HW + hw0;
    const short* abase = kbf + ((size_t)b * KK + sr) * HW + hw0 + sj * 8;

    f32x4 stgB[2][4][2];
    s16x8 stgA[2];

#define LOADREG(set_, t_)                                                      \
    {                                                                          \
        _Pragma("unroll") for (int i = 0; i < 4; i++) {                        \
            const float* p_ = vbase + (size_t)(sr + i * 64) * HW               \
                              + (t_) * 64 + sj * 8;                            \
            stgB[set_][i][0] = *(const f32x4*)p_;                              \
            stgB[set_][i][1] = *(const f32x4*)(p_ + 4);                        \
        }                                                                      \
        stgA[set_] = *(const s16x8*)(abase + (t_) * 64);                       \
    }
#define WRITE_LDS(set_, buf_)                                                  \
    {                                                                          \
        _Pragma("unroll") for (int i = 0; i < 4; i++) {                        \
            const int r_ = sr + i * 64;                                        \
            s16x8 tv_;                                                         \
            _Pragma("unroll") for (int e = 0; e < 4; e++) {                    \
                tv_[e]     = f2bf(stgB[set_][i][0][e]);                        \
                tv_[4 + e] = f2bf(stgB[set_][i][1][e]);                        \
            }                                                                  \
            *(s16x8*)&Bs[buf_][r_ * 64 + ((sj ^ (r_ & 7)) * 8)] = tv_;         \
        }                                                                      \
        *(s16x8*)&As[buf_][sr * 64 + ((sj ^ (sr & 7)) * 8)] = stgA[set_];      \
    }

    f32x4 acc[2][4];                    // [c-tile m2][k-tile n4]
#pragma unroll
    for (int m2 = 0; m2 < 2; m2++)
#pragma unroll
        for (int n4 = 0; n4 < 4; n4++) acc[m2][n4] = (f32x4){0.f, 0.f, 0.f, 0.f};

    // prologue
    LOADREG(0, 0);
    LOADREG(1, 1);
    WRITE_LDS(0, 0);
    asm volatile("s_waitcnt lgkmcnt(0)" ::: "memory");
    __builtin_amdgcn_s_barrier();

#pragma unroll
    for (int t = 0; t < 4; t++) {
        const int buf = t & 1;
        if (t + 2 < 4) LOADREG(buf, t + 2);          // HBM prefetch, 2 ahead
        if (t + 1 < 4) WRITE_LDS((t + 1) & 1, (t + 1) & 1);  // stage NEXT buffer

        const int swz = l15 & 7;
#pragma unroll
        for (int s = 0; s < 2; s++) {
            s16x8 vfr[2];
#pragma unroll
            for (int m2 = 0; m2 < 2; m2++)
                vfr[m2] = *(const s16x8*)&Bs[buf][(w * 32 + m2 * 16 + l15) * 64 +
                                                 (((s * 4 + hi) ^ swz) * 8)];
#pragma unroll
            for (int n4 = 0; n4 < 4; n4++) {
                const s16x8 afr = *(const s16x8*)&As[buf][(n4 * 16 + l15) * 64 +
                                                          (((s * 4 + hi) ^ swz) * 8)];
                acc[0][n4] = __builtin_amdgcn_mfma_f32_16x16x32_bf16(vfr[0], afr,
                                                                     acc[0][n4], 0, 0, 0);
                acc[1][n4] = __builtin_amdgcn_mfma_f32_16x16x32_bf16(vfr[1], afr,
                                                                     acc[1][n4], 0, 0, 0);
            }
        }
        if (t + 1 < 4) {
            asm volatile("s_waitcnt lgkmcnt(0)" ::: "memory");
            __builtin_amdgcn_s_barrier();            // single barrier per iter
        }
    }
#undef LOADREG
#undef WRITE_LDS

    // bf16 partial, store-order-native layout, chunk radix 8 (8 waves)
#pragma unroll
    for (int m2 = 0; m2 < 2; m2++)
#pragma unroll
        for (int n4 = 0; n4 < 4; n4++) {
            s16x4 v;
#pragma unroll
            for (int r = 0; r < 4; r++) v[r] = f2bf(acc[m2][n4][r]);
            *(s16x4*)(pbuf + ((((size_t)(id * 8 + w) * 2 + m2) * 4 + n4) * 64
                              + lane) * 4) = v;
        }
}

// ---------------------------------------------------------------------------
// K_cr (fused combine + readout): grid = bn(32) x ct(16) = 512 blocks,
// 512 threads (8 waves). Phase A (combine + gates) on tid<256.
// Phase B: LDS store-transpose -> 1KB fully-contiguous stores (r18), with
// raw s_barrier + lgkmcnt ONLY (no vmcnt drain) per iteration so the global
// store stream stays in flight across iterations (barrier-drain fix; the
// osb double-buffer only needs LDS ordering, which the barrier + per-wave
// in-order lgkm consumption already guarantee).
// ---------------------------------------------------------------------------
__global__ __launch_bounds__(512) void k_cr(const short* __restrict__ pbuf,
                                            const float* __restrict__ gram,
                                            const float* __restrict__ state,
                                            const float* __restrict__ betaH,
                                            const float* __restrict__ alphaH,
                                            const short* __restrict__ kbfT,
                                            float* __restrict__ out) {
    const int tid = threadIdx.x;
    const int id = blockIdx.x;        // bn*16 + ct
    const int ct = id & 15;
    const int bn = id >> 4;
    const int b  = bn >> 4;
    const int head = ct >> 1;
    const int wi = ct >> 1, m2 = ct & 1;

    __shared__ float gramL[KK][65];
    __shared__ float stL[KK][17];
    __shared__ float alphaL[KK], betaL[KK];
    __shared__ float nsb[KK][17];
    __shared__ short nsB[16][72];       // bf16, k-contiguous, padded
    __shared__ float osb[2][16][260];   // store-transpose tile, 2-way banks

    for (int i = tid; i < KK * KK; i += 512)
        gramL[i >> 6][i & 63] = gram[(size_t)b * KK * KK + i];
    for (int i = tid; i < KK * 16; i += 512)
        stL[i >> 4][i & 15] = state[((size_t)bn * KK + (i >> 4)) * CC + ct * 16 + (i & 15)];
    if (tid < KK) {
        alphaL[tid] = alphaH[((size_t)bn * KK + tid) * NH + head];
        betaL[tid]  = betaH[((size_t)bn * KK + tid) * NH + head];
    }
    __syncthreads();

    if (tid < 256) {
        const int k = tid >> 2, cq = (tid & 3) * 4;
        const int n4 = k >> 4, l15k = k & 15, hi4 = tid & 3;

        float vkt[4] = {0.f, 0.f, 0.f, 0.f};
#pragma unroll
        for (int hs = 0; hs < 16; hs++) {
            const int slab = bn * 16 + hs;
            const s16x4 p = *(const s16x4*)(pbuf +
                ((((size_t)(slab * 8 + wi) * 2 + m2) * 4 + n4) * 64 + hi4 * 16 + l15k) * 4);
#pragma unroll
            for (int i = 0; i < 4; i++) vkt[i] += bf2f(p[i]);
        }

        float vk[4] = {0.f, 0.f, 0.f, 0.f};
#pragma unroll 8
        for (int j = 0; j < KK; j++) {
            const float g = gramL[k][j];
            vk[0] = fmaf(g, stL[j][cq + 0], vk[0]);
            vk[1] = fmaf(g, stL[j][cq + 1], vk[1]);
            vk[2] = fmaf(g, stL[j][cq + 2], vk[2]);
            vk[3] = fmaf(g, stL[j][cq + 3], vk[3]);
        }
        const float al = alphaL[k], be = betaL[k];
#pragma unroll
        for (int i = 0; i < 4; i++)
            nsb[k][cq + i] = al * (stL[k][cq + i] - be * vk[i]) + be * vkt[i];
    }
    __syncthreads();

    if (tid < 256) {   // nsb (f32, [k][c]) -> nsB (bf16, [c][k])
        const int c = tid >> 4, k4 = (tid & 15) * 4;
        s16x4 v;
#pragma unroll
        for (int i = 0; i < 4; i++) v[i] = f2bf(nsb[k4 + i][c]);
        *(s16x4*)&nsB[c][k4] = v;
    }
    __syncthreads();

    // ---------------- phase B: readout with LDS store-transpose ----------------
    const int w8 = tid >> 6, lane = tid & 63;
    const int l15 = lane & 15, hi = lane >> 4;

    const s16x8 cf0 = *(const s16x8*)&nsB[l15][hi * 8];        // B-frag, k 0..31
    const s16x8 cf1 = *(const s16x8*)&nsB[l15][32 + hi * 8];   // B-frag, k 32..63

    const short* kb = kbfT + ((size_t)b * HW + l15) * KK + hi * 8;
    const int sc = tid >> 6;            // store row c (0..7, +8 second pass)
    const int sch = tid & 63;           // store chunk (x f32x4)
    float* orow0 = out + ((size_t)bn * CC + ct * 16 + sc) * HW;
    float* orow1 = out + ((size_t)bn * CC + ct * 16 + sc + 8) * HW;

#pragma unroll 2
    for (int it = 0; it < 16; ++it) {   // 256 hw per iter
        const int hwb = it * 256;
        const int pb = it & 1;
#pragma unroll
        for (int t = 0; t < 2; ++t) {
            const int hw0 = hwb + w8 * 32 + t * 16;
            const short* Bp = kb + (size_t)hw0 * KK;
            const s16x8 hwf0 = *(const s16x8*)Bp;
            const s16x8 hwf1 = *(const s16x8*)(Bp + 32);
            f32x4 acc = (f32x4){0.f, 0.f, 0.f, 0.f};
            acc = __builtin_amdgcn_mfma_f32_16x16x32_bf16(hwf0, cf0, acc, 0, 0, 0);
            acc = __builtin_amdgcn_mfma_f32_16x16x32_bf16(hwf1, cf1, acc, 0, 0, 0);
            // D: col = l15 = c, row = hi*4+r = hw offset within 16-hw tile
            *(f32x4*)&osb[pb][l15][w8 * 32 + t * 16 + hi * 4] = acc;
        }
        // LDS-only barrier: global stores from previous iters stay in flight
        asm volatile("s_waitcnt lgkmcnt(0)" ::: "memory");
        __builtin_amdgcn_s_barrier();
        const f32x4 v0 = *(const f32x4*)&osb[pb][sc][sch * 4];
        const f32x4 v1 = *(const f32x4*)&osb[pb][sc + 8][sch * 4];
        *(f32x4*)&orow0[hwb + sch * 4] = v0;   // 1KB contiguous per wave
        *(f32x4*)&orow1[hwb + sch * 4] = v1;
    }
}

// ---------------------------------------------------------------------------
extern "C" void kernel_launch(void* const* d_in, const int* in_sizes, int n_in,
                              void* d_out, int out_size, void* d_ws, size_t ws_size,
                              hipStream_t stream) {
    const float* value   = (const float*)d_in[0];
    const float* key_map = (const float*)d_in[1];
    const float* state   = (const float*)d_in[2];
    const float* b_w     = (const float*)d_in[3];
    const float* a_w     = (const float*)d_in[4];
    const float* A_log   = (const float*)d_in[5];
    const float* dt_bias = (const float*)d_in[6];
    float* out = (float*)d_out;

    short* kbf   = (short*)d_ws;              // B*K*HW bf16     = 524288 sh
    short* kbfT  = kbf + 524288;              // B*HW*K bf16     = 524288 sh
    float* gram  = (float*)(kbfT + 524288);   // B*K*K           =   8192 f32
    float* betaH = gram + 8192;               // B*N*K*NH        =  16384 f32
    float* alphaH= betaH + 16384;             // B*N*K*NH        =  16384 f32
    short* pbufB = (short*)(alphaH + 16384);  // 512*16384 bf16  = 16 MB
    // total ~18.5 MB of d_ws

    k_pre<<<BB * NN * KK + BB * (HW / 128), 256, 0, stream>>>(
        state, b_w, a_w, A_log, dt_bias, betaH, alphaH, key_map, kbf, kbfT);
    k_gram<<<BB * (KK * (KK + 1) / 2), 256, 0, stream>>>(kbf, gram);
    k_vkt_part<<<BB * NN * 16, 512, 0, stream>>>(kbf, value, pbufB);
    k_cr<<<BB * NN * 16, 512, 0, stream>>>(pbufB, gram, state, betaH, alphaH,
                                           kbfT, out);
}